// Round 3
// baseline (338.252 us; speedup 1.0000x reference)
//
#include <hip/hip_runtime.h>
#include <math.h>

#define B_  16
#define T_  512
#define S_  1024
#define E_  1024
#define D_  1024

using short8   = __attribute__((ext_vector_type(8))) short;
using float4v  = __attribute__((ext_vector_type(4))) float;

__device__ __forceinline__ unsigned short f2bf(float f) {
    unsigned u = __builtin_bit_cast(unsigned, f);
    u += 0x7fff + ((u >> 16) & 1);          // round-to-nearest-even
    return (unsigned short)(u >> 16);
}

__device__ __forceinline__ void gl_lds16(const void* g, void* l) {
    __builtin_amdgcn_global_load_lds(
        (const __attribute__((address_space(1))) void*)g,
        (__attribute__((address_space(3))) void*)l, 16, 0, 0);
}

// ---------------------------------------------------------------------------
// Combined prep: transpose+cast W (z==16) and EV (z<16).
// src (1024 x 1024) fp32 row-major -> dst (1024 x 1024) bf16 transposed.
// ---------------------------------------------------------------------------
__global__ __launch_bounds__(256)
void prep_transposes(const float* __restrict__ W, unsigned short* __restrict__ WT,
                     const float* __restrict__ ev, unsigned short* __restrict__ EVT)
{
    __shared__ unsigned short tile[64][65];
    const int z = blockIdx.z;
    const float* src;
    unsigned short* dst;
    if (z == 16) { src = W; dst = WT; }
    else         { src = ev + (long long)z * S_ * D_; dst = EVT + (long long)z * D_ * S_; }
    const int RC = 1024;                    // both matrices are 1024x1024
    const int c0 = blockIdx.x * 64;
    const int r0 = blockIdx.y * 64;
    const int t = threadIdx.x;

    #pragma unroll
    for (int it = 0; it < 4; ++it) {
        int r  = (t >> 4) + it * 16;
        int c4 = (t & 15) << 2;
        float4 v = *(const float4*)&src[(long long)(r0 + r) * RC + c0 + c4];
        tile[r][c4 + 0] = f2bf(v.x);
        tile[r][c4 + 1] = f2bf(v.y);
        tile[r][c4 + 2] = f2bf(v.z);
        tile[r][c4 + 3] = f2bf(v.w);
    }
    __syncthreads();
    #pragma unroll
    for (int it = 0; it < 2; ++it) {
        int c  = (t >> 3) + it * 32;
        int r8 = (t & 7) << 3;
        short8 sv;
        #pragma unroll
        for (int j = 0; j < 8; ++j) sv[j] = (short)tile[r8 + j][c];
        *(short8*)&dst[(long long)(c0 + c) * RC + r0 + r8] = sv;
    }
}

// ---------------------------------------------------------------------------
// MFMA GEMM: C[M,N] = A @ B^T.  A (M,K), B (N,K) row-major.
// Either operand may be fp32-in-global (A_F32/B_F32): it is then reg-staged
// (global f32 loads issued BEFORE compute, cvt+ds_write after — T14 split),
// converting to bf16 on the fly; the bf16 operand uses global_load_lds w=16.
// 128x128 tile, BK=64 as two [128][32] subtiles (m97 lane mapping),
// double-buffered LDS, 16x16x32 MFMA, 4 waves of 64x64.
// ---------------------------------------------------------------------------
template<bool A_F32, bool B_F32, bool OUT_BF16, bool CMASK>
__global__ __launch_bounds__(256, 2)
void mfma_gemm2(const void* __restrict__ Ap, const void* __restrict__ Bp,
                const float* __restrict__ mask, void* __restrict__ Cp,
                int N, int K,
                long long sA, long long sB, long long sC, int maskStride)
{
    __shared__ unsigned short Asl[2][2 * 128 * 32];
    __shared__ unsigned short Bsl[2][2 * 128 * 32];

    const int z    = blockIdx.z;
    const int col0 = blockIdx.x * 128;
    const int row0 = blockIdx.y * 128;
    const int t    = threadIdx.x;
    const int lane = t & 63;
    const int wave = t >> 6;

    const unsigned short* Ab = A_F32 ? nullptr
        : (const unsigned short*)Ap + z * sA + (long long)row0 * K;
    const float* Af = A_F32 ? (const float*)Ap + z * sA + (long long)row0 * K : nullptr;
    const unsigned short* Bb = B_F32 ? nullptr
        : (const unsigned short*)Bp + z * sB + (long long)col0 * K;
    const float* Bf = B_F32 ? (const float*)Bp + z * sB + (long long)col0 * K : nullptr;

    // staging map: chunk c = it*256 + t -> row c>>2, k-chunk (c&3)*8 of a
    // [128][32] subtile; LDS dest byte = j*8192 + it*4096 + wave*1024 + lane*16.
    const int rs  = t >> 2;
    const int kcs = (t & 3) << 3;
    const unsigned ldsW = wave * 1024;

    const int wm = (wave >> 1) * 64;
    const int wn = (wave & 1) * 64;
    const int fr = lane & 15;
    const int fg = lane >> 4;

    float4v acc[4][4];
    #pragma unroll
    for (int i = 0; i < 4; ++i)
        #pragma unroll
        for (int j = 0; j < 4; ++j)
            acc[i][j] = (float4v)0.0f;

    float4 aReg[2][2][2];   // [j][it][half] — only if A_F32
    float4 bReg[2][2][2];   // only if B_F32

    // issue global loads: f32 operand -> regs FIRST, then bf16 operand gl_lds
    auto STAGE_LOAD = [&](int bufi, int k0) {
        #pragma unroll
        for (int j = 0; j < 2; ++j)
            #pragma unroll
            for (int it = 0; it < 2; ++it) {
                const int r = rs + it * 64;
                const long long goff = (long long)r * K + k0 + j * 32 + kcs;
                if constexpr (A_F32) {
                    aReg[j][it][0] = *(const float4*)(Af + goff);
                    aReg[j][it][1] = *(const float4*)(Af + goff + 4);
                }
                if constexpr (B_F32) {
                    bReg[j][it][0] = *(const float4*)(Bf + goff);
                    bReg[j][it][1] = *(const float4*)(Bf + goff + 4);
                }
            }
        #pragma unroll
        for (int j = 0; j < 2; ++j)
            #pragma unroll
            for (int it = 0; it < 2; ++it) {
                const int r = rs + it * 64;
                const long long goff = (long long)r * K + k0 + j * 32 + kcs;
                const unsigned loff = j * 8192 + it * 4096 + ldsW;
                if constexpr (!A_F32) gl_lds16(Ab + goff, (char*)&Asl[bufi][0] + loff);
                if constexpr (!B_F32) gl_lds16(Bb + goff, (char*)&Bsl[bufi][0] + loff);
            }
    };

    auto cvt8 = [](float4 a, float4 b) -> short8 {
        short8 o;
        o[0] = f2bf(a.x); o[1] = f2bf(a.y); o[2] = f2bf(a.z); o[3] = f2bf(a.w);
        o[4] = f2bf(b.x); o[5] = f2bf(b.y); o[6] = f2bf(b.z); o[7] = f2bf(b.w);
        return o;
    };

    // cvt + ds_write of the reg-staged operand (after compute, before barrier)
    auto STAGE_WRITE = [&](int bufi) {
        #pragma unroll
        for (int j = 0; j < 2; ++j)
            #pragma unroll
            for (int it = 0; it < 2; ++it) {
                const unsigned loff = j * 8192 + it * 4096 + ldsW + lane * 16;
                if constexpr (A_F32)
                    *(short8*)((char*)&Asl[bufi][0] + loff) = cvt8(aReg[j][it][0], aReg[j][it][1]);
                if constexpr (B_F32)
                    *(short8*)((char*)&Bsl[bufi][0] + loff) = cvt8(bReg[j][it][0], bReg[j][it][1]);
            }
    };

    auto COMPUTE = [&](int bufi) {
        short8 afr[2][4], bfr[2][4];
        #pragma unroll
        for (int j = 0; j < 2; ++j) {
            #pragma unroll
            for (int mi = 0; mi < 4; ++mi)
                afr[j][mi] = *(const short8*)&Asl[bufi][j * 4096 + (wm + mi * 16 + fr) * 32 + fg * 8];
            #pragma unroll
            for (int ni = 0; ni < 4; ++ni)
                bfr[j][ni] = *(const short8*)&Bsl[bufi][j * 4096 + (wn + ni * 16 + fr) * 32 + fg * 8];
        }
        #pragma unroll
        for (int j = 0; j < 2; ++j)
            #pragma unroll
            for (int mi = 0; mi < 4; ++mi)
                #pragma unroll
                for (int ni = 0; ni < 4; ++ni)
                    acc[mi][ni] = __builtin_amdgcn_mfma_f32_16x16x32_bf16(afr[j][mi], bfr[j][ni], acc[mi][ni], 0, 0, 0);
    };

    // prologue
    STAGE_LOAD(0, 0);
    STAGE_WRITE(0);
    __syncthreads();

    int buf = 0;
    for (int k0 = 64; k0 <= K; k0 += 64) {
        if (k0 < K) STAGE_LOAD(buf ^ 1, k0);   // next-tile loads in flight
        COMPUTE(buf);
        if (k0 < K) STAGE_WRITE(buf ^ 1);      // cvt hides under MFMA latency
        __syncthreads();
        buf ^= 1;
    }

    float mv[4];
    #pragma unroll
    for (int ni = 0; ni < 4; ++ni) {
        int ocol = col0 + wn + ni * 16 + fr;
        mv[ni] = CMASK ? mask[(long long)z * maskStride + ocol] : 1.0f;
    }
    #pragma unroll
    for (int mi = 0; mi < 4; ++mi) {
        #pragma unroll
        for (int ni = 0; ni < 4; ++ni) {
            int ocol = col0 + wn + ni * 16 + fr;
            #pragma unroll
            for (int r = 0; r < 4; ++r) {
                int orow = row0 + wm + mi * 16 + fg * 4 + r;
                float v = acc[mi][ni][r] * mv[ni];
                if (OUT_BF16)
                    ((unsigned short*)Cp)[z * sC + (long long)orow * N + ocol] = f2bf(v);
                else
                    ((float*)Cp)[z * sC + (long long)orow * N + ocol] = v;
            }
        }
    }
}

// ---------------------------------------------------------------------------
// Masked softmax over rows of ae -> aw (fp32 only; K4 reads aw directly).
// ---------------------------------------------------------------------------
__global__ __launch_bounds__(256)
void softmax_mask(const float* __restrict__ x, const float* __restrict__ mask,
                  float* __restrict__ w)
{
    const int row = blockIdx.x;
    const int b   = row >> 9;             // T_=512
    const float* xr = x    + (long long)row * S_;
    const float* mr = mask + (long long)b * S_;
    float*       wr = w    + (long long)row * S_;
    const int tid = threadIdx.x;

    float4 xv = ((const float4*)xr)[tid];
    float4 mv = ((const float4*)mr)[tid];

    float lmax = fmaxf(fmaxf(xv.x, xv.y), fmaxf(xv.z, xv.w));
    #pragma unroll
    for (int off = 32; off; off >>= 1)
        lmax = fmaxf(lmax, __shfl_xor(lmax, off, 64));

    __shared__ float red[4];
    const int wave = tid >> 6, lane = tid & 63;
    if (lane == 0) red[wave] = lmax;
    __syncthreads();
    const float rmax = fmaxf(fmaxf(red[0], red[1]), fmaxf(red[2], red[3]));

    float e0 = expf(xv.x - rmax) * mv.x;
    float e1 = expf(xv.y - rmax) * mv.y;
    float e2 = expf(xv.z - rmax) * mv.z;
    float e3 = expf(xv.w - rmax) * mv.w;

    float lsum = (e0 + e1) + (e2 + e3);
    #pragma unroll
    for (int off = 32; off; off >>= 1)
        lsum += __shfl_xor(lsum, off, 64);

    __syncthreads();
    if (lane == 0) red[wave] = lsum;
    __syncthreads();
    const float rsum = (red[0] + red[1]) + (red[2] + red[3]);
    const float inv = 1.0f / (rsum + 1e-6f);

    float4 o;
    o.x = e0 * inv; o.y = e1 * inv; o.z = e2 * inv; o.w = e3 * inv;
    ((float4*)wr)[tid] = o;
}

// ---------------------------------------------------------------------------
// fp32 fallback GEMM — used only if d_ws is tiny.
// ---------------------------------------------------------------------------
constexpr int FBM = 64, FBN = 64, FBK = 16;
template<bool BT, bool CMASK>
__global__ __launch_bounds__(256)
void gemm_f32(const float* __restrict__ A, const float* __restrict__ Bm,
              const float* __restrict__ mask, float* __restrict__ C,
              int N_dim, int K_dim,
              long long sA, long long sB, long long sC, int maskStride)
{
    const int bz = blockIdx.z;
    A  += (long long)bz * sA;
    Bm += (long long)bz * sB;
    C  += (long long)bz * sC;
    __shared__ float As[FBK][FBM];
    __shared__ float Bs[FBK][FBN];
    const int tid  = threadIdx.x;
    const int row0 = blockIdx.y * FBM;
    const int col0 = blockIdx.x * FBN;
    const int lrow = tid >> 2;
    const int lk   = (tid & 3) << 2;
    const int bk = tid >> 4;
    const int bn = (tid & 15) << 2;
    const int tx = tid & 15;
    const int ty = tid >> 4;
    float acc[4][4] = {};
    const float* Aptr = A + (long long)(row0 + lrow) * K_dim + lk;
    const float* Bptr = BT ? (Bm + (long long)(col0 + lrow) * K_dim + lk)
                           : (Bm + (long long)bk * N_dim + col0 + bn);
    for (int k0 = 0; k0 < K_dim; k0 += FBK) {
        float4 av = *(const float4*)(Aptr + k0);
        As[lk + 0][lrow] = av.x; As[lk + 1][lrow] = av.y;
        As[lk + 2][lrow] = av.z; As[lk + 3][lrow] = av.w;
        if (BT) {
            float4 bv = *(const float4*)(Bptr + k0);
            Bs[lk + 0][lrow] = bv.x; Bs[lk + 1][lrow] = bv.y;
            Bs[lk + 2][lrow] = bv.z; Bs[lk + 3][lrow] = bv.w;
        } else {
            float4 bv = *(const float4*)(Bptr + (long long)k0 * N_dim);
            *(float4*)&Bs[bk][bn] = bv;
        }
        __syncthreads();
        #pragma unroll
        for (int k = 0; k < FBK; ++k) {
            float4 a4 = *(const float4*)&As[k][ty << 2];
            float4 b4 = *(const float4*)&Bs[k][tx << 2];
            float ar[4] = {a4.x, a4.y, a4.z, a4.w};
            float br[4] = {b4.x, b4.y, b4.z, b4.w};
            #pragma unroll
            for (int i = 0; i < 4; ++i)
                #pragma unroll
                for (int j = 0; j < 4; ++j)
                    acc[i][j] = fmaf(ar[i], br[j], acc[i][j]);
        }
        __syncthreads();
    }
    float mvv[4] = {1.f, 1.f, 1.f, 1.f};
    if (CMASK) {
        #pragma unroll
        for (int j = 0; j < 4; ++j)
            mvv[j] = mask[(long long)bz * maskStride + col0 + (tx << 2) + j];
    }
    #pragma unroll
    for (int i = 0; i < 4; ++i) {
        const int r = row0 + (ty << 2) + i;
        float4 o;
        o.x = acc[i][0] * mvv[0]; o.y = acc[i][1] * mvv[1];
        o.z = acc[i][2] * mvv[2]; o.w = acc[i][3] * mvv[3];
        *(float4*)&C[(long long)r * N_dim + col0 + (tx << 2)] = o;
    }
}

extern "C" void kernel_launch(void* const* d_in, const int* in_sizes, int n_in,
                              void* d_out, int out_size, void* d_ws, size_t ws_size,
                              hipStream_t stream)
{
    const float* hidden = (const float*)d_in[0];   // (B,T,D)
    const float* eo     = (const float*)d_in[1];   // (B,S,E)
    const float* ev     = (const float*)d_in[2];   // (B,S,D)
    const float* mask   = (const float*)d_in[3];   // (B,S)
    const float* W      = (const float*)d_in[4];   // (D,E)

    float* out = (float*)d_out;
    const long long CTX = (long long)B_ * T_ * D_;
    float* ctx = out;
    float* aw  = out + CTX;
    float* ae  = out + 2 * CTX;

    dim3 blk(256);
    const size_t MB = 1024ull * 1024ull;
    const size_t NEED_FAST = 50 * MB;

    if (ws_size >= NEED_FAST) {
        // workspace: WT [0,2) MB | EVT [2,34) MB | G [34,50) MB
        char* ws = (char*)d_ws;
        unsigned short* WT  = (unsigned short*)(ws);
        unsigned short* EVT = (unsigned short*)(ws + 2 * MB);
        unsigned short* G   = (unsigned short*)(ws + 34 * MB);

        // prep: WT = W^T (bf16), EVT[b] = EV[b]^T (bf16)
        prep_transposes<<<dim3(16, 16, 17), blk, 0, stream>>>(W, WT, ev, EVT);

        // K1: G = bf16(H) @ WT^T -> bf16  (A = hidden fp32, reg-staged)
        mfma_gemm2<true, false, true, false>
            <<<dim3(E_ / 128, (B_ * T_) / 128, 1), blk, 0, stream>>>(
            hidden, WT, nullptr, G, E_, D_, 0, 0, 0, 0);

        // K2: ae[b,t,s] = mask[b,s] * (G[b,t,:] . bf16(EO[b,s,:]))
        //     (B = encoder_outputs fp32, reg-staged)
        mfma_gemm2<false, true, false, true>
            <<<dim3(S_ / 128, T_ / 128, B_), blk, 0, stream>>>(
            G, eo, mask, ae, S_, E_,
            (long long)T_ * E_, (long long)S_ * E_, (long long)T_ * S_, S_);

        // K3: softmax -> aw (fp32)
        softmax_mask<<<dim3(B_ * T_), blk, 0, stream>>>(ae, mask, aw);

        // K4: ctx = bf16(aw) @ EVT^T   (A = aw fp32, reg-staged)
        mfma_gemm2<true, false, false, false>
            <<<dim3(D_ / 128, T_ / 128, B_), blk, 0, stream>>>(
            aw, EVT, nullptr, ctx, D_, S_,
            (long long)T_ * S_, (long long)D_ * S_, (long long)T_ * D_, 0);
    } else {
        float* G = aw;
        gemm_f32<false, false><<<dim3(E_ / FBN, (B_ * T_) / FBM, 1), blk, 0, stream>>>(
            hidden, W, nullptr, G, E_, D_, 0, 0, 0, 0);
        gemm_f32<true, true><<<dim3(S_ / FBN, T_ / FBM, B_), blk, 0, stream>>>(
            G, eo, mask, ae, S_, E_,
            (long long)T_ * E_, (long long)S_ * E_, (long long)T_ * S_, S_);
        softmax_mask<<<dim3(B_ * T_), blk, 0, stream>>>(ae, mask, aw);
        gemm_f32<false, false><<<dim3(D_ / FBN, T_ / FBM, B_), blk, 0, stream>>>(
            aw, ev, nullptr, ctx, D_, S_,
            (long long)T_ * S_, (long long)S_ * D_, (long long)T_ * D_, 0);
    }
}

// Round 4
// 333.445 us; speedup vs baseline: 1.0144x; 1.0144x over previous
//
#include <hip/hip_runtime.h>
#include <math.h>

#define B_  16
#define T_  512
#define S_  1024
#define E_  1024
#define D_  1024

using short8   = __attribute__((ext_vector_type(8))) short;
using ushort4v = __attribute__((ext_vector_type(4))) unsigned short;
using float4v  = __attribute__((ext_vector_type(4))) float;

__device__ __forceinline__ unsigned short f2bf(float f) {
    unsigned u = __builtin_bit_cast(unsigned, f);
    u += 0x7fff + ((u >> 16) & 1);          // round-to-nearest-even
    return (unsigned short)(u >> 16);
}

__device__ __forceinline__ void gl_lds16(const void* g, void* l) {
    __builtin_amdgcn_global_load_lds(
        (const __attribute__((address_space(1))) void*)g,
        (__attribute__((address_space(3))) void*)l, 16, 0, 0);
}

// ---------------------------------------------------------------------------
// Elementwise fp32 -> bf16 cast, 8 elements/thread.
// ---------------------------------------------------------------------------
__global__ __launch_bounds__(256)
void cast_bf16(const float* __restrict__ src, unsigned short* __restrict__ dst, int n8)
{
    int i = blockIdx.x * 256 + threadIdx.x;
    if (i < n8) {
        float4 a = ((const float4*)src)[2 * i];
        float4 b = ((const float4*)src)[2 * i + 1];
        short8 o;
        o[0] = f2bf(a.x); o[1] = f2bf(a.y); o[2] = f2bf(a.z); o[3] = f2bf(a.w);
        o[4] = f2bf(b.x); o[5] = f2bf(b.y); o[6] = f2bf(b.z); o[7] = f2bf(b.w);
        ((short8*)dst)[i] = o;
    }
}

// ---------------------------------------------------------------------------
// Transpose+cast: src (R x C) fp32 row-major -> dst (C x R) bf16 row-major.
// ---------------------------------------------------------------------------
__global__ __launch_bounds__(256)
void transpose_cast(const float* __restrict__ src, unsigned short* __restrict__ dst,
                    int R, int C, long long sSrc, long long sDst)
{
    __shared__ unsigned short tile[64][65];
    const int z = blockIdx.z;
    src += (long long)z * sSrc;
    dst += (long long)z * sDst;
    const int c0 = blockIdx.x * 64;
    const int r0 = blockIdx.y * 64;
    const int t = threadIdx.x;

    #pragma unroll
    for (int it = 0; it < 4; ++it) {
        int r  = (t >> 4) + it * 16;
        int c4 = (t & 15) << 2;
        float4 v = *(const float4*)&src[(long long)(r0 + r) * C + c0 + c4];
        tile[r][c4 + 0] = f2bf(v.x);
        tile[r][c4 + 1] = f2bf(v.y);
        tile[r][c4 + 2] = f2bf(v.z);
        tile[r][c4 + 3] = f2bf(v.w);
    }
    __syncthreads();
    #pragma unroll
    for (int it = 0; it < 2; ++it) {
        int c  = (t >> 3) + it * 32;
        int r8 = (t & 7) << 3;
        short8 sv;
        #pragma unroll
        for (int j = 0; j < 8; ++j) sv[j] = (short)tile[r8 + j][c];
        *(short8*)&dst[(long long)(c0 + c) * R + r0 + r8] = sv;
    }
}

// ---------------------------------------------------------------------------
// MFMA GEMM: C[M,N] = A @ B^T, A (M,K) bf16, B (N,K) bf16, row-major.
// ROUND 4: tile 128x64 (BM x BN) instead of 128x128 — grid doubles to
// 1024 blocks = 4 blocks/CU (the m102 occupancy lever: 1/CU->320 TF,
// 4/CU->874 TF).  Single-buffered LDS 24 KB, two barriers per K-step
// (the verified R0 loop — R1 showed dbuf is neutral here).  BK=64 as two
// [.][32] subtiles with the m97-validated lane mapping.  4 waves: wave
// tile 64x32, acc 4x2 frags, 16 MFMA / 12 ds_read_b128 per K-step.
// ---------------------------------------------------------------------------
template<bool OUT_BF16, bool CMASK>
__global__ __launch_bounds__(256, 4)
void mfma_gemm_bf(const unsigned short* __restrict__ Ap,
                  const unsigned short* __restrict__ Bp,
                  const float* __restrict__ mask, void* __restrict__ Cp,
                  int N, int K,
                  long long sA, long long sB, long long sC, int maskStride)
{
    __shared__ unsigned short Asl[2 * 128 * 32];   // subtile j at j*4096 elems
    __shared__ unsigned short Bsl[2 * 64 * 32];    // subtile j at j*2048 elems

    const int z    = blockIdx.z;
    const int col0 = blockIdx.x * 64;
    const int row0 = blockIdx.y * 128;
    const int t    = threadIdx.x;
    const int lane = t & 63;
    const int wave = t >> 6;

    const unsigned short* A  = Ap + z * sA + (long long)row0 * K;
    const unsigned short* Bm = Bp + z * sB + (long long)col0 * K;

    // staging map (m97-validated): chunk c covers row c>>2, k-chunk (c&3)*8
    // of a [rows][32] subtile; LDS dest byte = subtile_base + c*16, expressed
    // as wave-uniform base + lane*16.
    const int rs  = t >> 2;              // [0,64)
    const int kcs = (t & 3) << 3;
    const unsigned ldsW = wave * 1024;   // bytes

    const int wm = (wave >> 1) * 64;     // {0,64}
    const int wn = (wave & 1) * 32;      // {0,32}
    const int fr = lane & 15;
    const int fg = lane >> 4;

    float4v acc[4][2];
    #pragma unroll
    for (int i = 0; i < 4; ++i)
        #pragma unroll
        for (int j = 0; j < 2; ++j)
            acc[i][j] = (float4v)0.0f;

    for (int k0 = 0; k0 < K; k0 += 64) {
        // stage A: 128 rows -> j2 x it2 chunks of [64 rows]
        #pragma unroll
        for (int j = 0; j < 2; ++j) {
            #pragma unroll
            for (int it = 0; it < 2; ++it) {
                const int r = rs + it * 64;
                const long long goff = (long long)r * K + k0 + j * 32 + kcs;
                const unsigned loff = j * 8192 + it * 4096 + ldsW;   // bytes
                gl_lds16(A + goff, (char*)Asl + loff);
            }
        }
        // stage B: 64 rows -> j2 chunks
        #pragma unroll
        for (int j = 0; j < 2; ++j) {
            const long long goff = (long long)rs * K + k0 + j * 32 + kcs;
            const unsigned loff = j * 4096 + ldsW;                   // bytes
            gl_lds16(Bm + goff, (char*)Bsl + loff);
        }
        __syncthreads();

        short8 af[2][4], bfr[2][2];
        #pragma unroll
        for (int j = 0; j < 2; ++j) {
            #pragma unroll
            for (int mi = 0; mi < 4; ++mi)
                af[j][mi] = *(const short8*)&Asl[j * 4096 + (wm + mi * 16 + fr) * 32 + fg * 8];
            #pragma unroll
            for (int ni = 0; ni < 2; ++ni)
                bfr[j][ni] = *(const short8*)&Bsl[j * 2048 + (wn + ni * 16 + fr) * 32 + fg * 8];
        }
        #pragma unroll
        for (int j = 0; j < 2; ++j)
            #pragma unroll
            for (int mi = 0; mi < 4; ++mi)
                #pragma unroll
                for (int ni = 0; ni < 2; ++ni)
                    acc[mi][ni] = __builtin_amdgcn_mfma_f32_16x16x32_bf16(af[j][mi], bfr[j][ni], acc[mi][ni], 0, 0, 0);
        __syncthreads();
    }

    float mv[2];
    #pragma unroll
    for (int ni = 0; ni < 2; ++ni) {
        int ocol = col0 + wn + ni * 16 + fr;
        mv[ni] = CMASK ? mask[(long long)z * maskStride + ocol] : 1.0f;
    }
    #pragma unroll
    for (int mi = 0; mi < 4; ++mi) {
        #pragma unroll
        for (int ni = 0; ni < 2; ++ni) {
            int ocol = col0 + wn + ni * 16 + fr;
            #pragma unroll
            for (int r = 0; r < 4; ++r) {
                int orow = row0 + wm + mi * 16 + fg * 4 + r;
                float v = acc[mi][ni][r] * mv[ni];
                if (OUT_BF16)
                    ((unsigned short*)Cp)[z * sC + (long long)orow * N + ocol] = f2bf(v);
                else
                    ((float*)Cp)[z * sC + (long long)orow * N + ocol] = v;
            }
        }
    }
}

// ---------------------------------------------------------------------------
// Masked softmax; also writes a bf16 copy of the weights when wbf != nullptr.
// ---------------------------------------------------------------------------
__global__ __launch_bounds__(256)
void softmax_mask(const float* __restrict__ x, const float* __restrict__ mask,
                  float* __restrict__ w, unsigned short* __restrict__ wbf)
{
    const int row = blockIdx.x;
    const int b   = row >> 9;             // T_=512
    const float* xr = x    + (long long)row * S_;
    const float* mr = mask + (long long)b * S_;
    float*       wr = w    + (long long)row * S_;
    const int tid = threadIdx.x;

    float4 xv = ((const float4*)xr)[tid];
    float4 mv = ((const float4*)mr)[tid];

    float lmax = fmaxf(fmaxf(xv.x, xv.y), fmaxf(xv.z, xv.w));
    #pragma unroll
    for (int off = 32; off; off >>= 1)
        lmax = fmaxf(lmax, __shfl_xor(lmax, off, 64));

    __shared__ float red[4];
    const int wave = tid >> 6, lane = tid & 63;
    if (lane == 0) red[wave] = lmax;
    __syncthreads();
    const float rmax = fmaxf(fmaxf(red[0], red[1]), fmaxf(red[2], red[3]));

    float e0 = expf(xv.x - rmax) * mv.x;
    float e1 = expf(xv.y - rmax) * mv.y;
    float e2 = expf(xv.z - rmax) * mv.z;
    float e3 = expf(xv.w - rmax) * mv.w;

    float lsum = (e0 + e1) + (e2 + e3);
    #pragma unroll
    for (int off = 32; off; off >>= 1)
        lsum += __shfl_xor(lsum, off, 64);

    __syncthreads();
    if (lane == 0) red[wave] = lsum;
    __syncthreads();
    const float rsum = (red[0] + red[1]) + (red[2] + red[3]);
    const float inv = 1.0f / (rsum + 1e-6f);

    float4 o;
    o.x = e0 * inv; o.y = e1 * inv; o.z = e2 * inv; o.w = e3 * inv;
    ((float4*)wr)[tid] = o;
    if (wbf) {
        ushort4v u;
        u[0] = f2bf(o.x); u[1] = f2bf(o.y); u[2] = f2bf(o.z); u[3] = f2bf(o.w);
        ((ushort4v*)(wbf + (long long)row * S_))[tid] = u;
    }
}

// ---------------------------------------------------------------------------
// fp32 fallback GEMM — used only if d_ws is tiny.
// ---------------------------------------------------------------------------
constexpr int FBM = 64, FBN = 64, FBK = 16;
template<bool BT, bool CMASK>
__global__ __launch_bounds__(256)
void gemm_f32(const float* __restrict__ A, const float* __restrict__ Bm,
              const float* __restrict__ mask, float* __restrict__ C,
              int N_dim, int K_dim,
              long long sA, long long sB, long long sC, int maskStride)
{
    const int bz = blockIdx.z;
    A  += (long long)bz * sA;
    Bm += (long long)bz * sB;
    C  += (long long)bz * sC;
    __shared__ float As[FBK][FBM];
    __shared__ float Bs[FBK][FBN];
    const int tid  = threadIdx.x;
    const int row0 = blockIdx.y * FBM;
    const int col0 = blockIdx.x * FBN;
    const int lrow = tid >> 2;
    const int lk   = (tid & 3) << 2;
    const int bk = tid >> 4;
    const int bn = (tid & 15) << 2;
    const int tx = tid & 15;
    const int ty = tid >> 4;
    float acc[4][4] = {};
    const float* Aptr = A + (long long)(row0 + lrow) * K_dim + lk;
    const float* Bptr = BT ? (Bm + (long long)(col0 + lrow) * K_dim + lk)
                           : (Bm + (long long)bk * N_dim + col0 + bn);
    for (int k0 = 0; k0 < K_dim; k0 += FBK) {
        float4 av = *(const float4*)(Aptr + k0);
        As[lk + 0][lrow] = av.x; As[lk + 1][lrow] = av.y;
        As[lk + 2][lrow] = av.z; As[lk + 3][lrow] = av.w;
        if (BT) {
            float4 bv = *(const float4*)(Bptr + k0);
            Bs[lk + 0][lrow] = bv.x; Bs[lk + 1][lrow] = bv.y;
            Bs[lk + 2][lrow] = bv.z; Bs[lk + 3][lrow] = bv.w;
        } else {
            float4 bv = *(const float4*)(Bptr + (long long)k0 * N_dim);
            *(float4*)&Bs[bk][bn] = bv;
        }
        __syncthreads();
        #pragma unroll
        for (int k = 0; k < FBK; ++k) {
            float4 a4 = *(const float4*)&As[k][ty << 2];
            float4 b4 = *(const float4*)&Bs[k][tx << 2];
            float ar[4] = {a4.x, a4.y, a4.z, a4.w};
            float br[4] = {b4.x, b4.y, b4.z, b4.w};
            #pragma unroll
            for (int i = 0; i < 4; ++i)
                #pragma unroll
                for (int j = 0; j < 4; ++j)
                    acc[i][j] = fmaf(ar[i], br[j], acc[i][j]);
        }
        __syncthreads();
    }
    float mvv[4] = {1.f, 1.f, 1.f, 1.f};
    if (CMASK) {
        #pragma unroll
        for (int j = 0; j < 4; ++j)
            mvv[j] = mask[(long long)bz * maskStride + col0 + (tx << 2) + j];
    }
    #pragma unroll
    for (int i = 0; i < 4; ++i) {
        const int r = row0 + (ty << 2) + i;
        float4 o;
        o.x = acc[i][0] * mvv[0]; o.y = acc[i][1] * mvv[1];
        o.z = acc[i][2] * mvv[2]; o.w = acc[i][3] * mvv[3];
        *(float4*)&C[(long long)r * N_dim + col0 + (tx << 2)] = o;
    }
}

extern "C" void kernel_launch(void* const* d_in, const int* in_sizes, int n_in,
                              void* d_out, int out_size, void* d_ws, size_t ws_size,
                              hipStream_t stream)
{
    const float* hidden = (const float*)d_in[0];   // (B,T,D)
    const float* eo     = (const float*)d_in[1];   // (B,S,E)
    const float* ev     = (const float*)d_in[2];   // (B,S,D)
    const float* mask   = (const float*)d_in[3];   // (B,S)
    const float* W      = (const float*)d_in[4];   // (D,E)

    float* out = (float*)d_out;
    const long long CTX = (long long)B_ * T_ * D_;
    float* ctx = out;
    float* aw  = out + CTX;
    float* ae  = out + 2 * CTX;

    dim3 blk(256);
    const size_t MB = 1024ull * 1024ull;
    const size_t NEED_FAST = 64 * MB;

    if (ws_size >= NEED_FAST) {
        // Phased workspace layout (aliasing by live range):
        //   [0,16)  Hbf  (dead after K1) -> EObf [0,32) after K1
        //   [16,18) WT   (dead after K1)
        //   [16,48) EVT  (written after K2)
        //   [48,64) G    (dead after K2) -> AWbf
        char* ws = (char*)d_ws;
        unsigned short* Hbf  = (unsigned short*)(ws);
        unsigned short* WT   = (unsigned short*)(ws + 16 * MB);
        unsigned short* EObf = (unsigned short*)(ws);
        unsigned short* EVT  = (unsigned short*)(ws + 16 * MB);
        unsigned short* G    = (unsigned short*)(ws + 48 * MB);
        unsigned short* AWbf = (unsigned short*)(ws + 48 * MB);

        cast_bf16<<<dim3((B_ * T_ * D_ / 8 + 255) / 256), blk, 0, stream>>>(
            hidden, Hbf, B_ * T_ * D_ / 8);
        transpose_cast<<<dim3(E_ / 64, D_ / 64, 1), blk, 0, stream>>>(
            W, WT, D_, E_, 0, 0);

        // K1: G = Hbf @ WT^T  -> bf16   (grid 16 x 64 = 1024 blocks)
        mfma_gemm_bf<true, false><<<dim3(E_ / 64, (B_ * T_) / 128, 1), blk, 0, stream>>>(
            Hbf, WT, nullptr, G, E_, D_, 0, 0, 0, 0);

        cast_bf16<<<dim3((B_ * S_ * E_ / 8 + 255) / 256), blk, 0, stream>>>(
            eo, EObf, B_ * S_ * E_ / 8);

        // K2: ae[b,t,s] = mask[b,s] * (G[b,t,:] . EObf[b,s,:])  (16x4x16 = 1024)
        mfma_gemm_bf<false, true><<<dim3(S_ / 64, T_ / 128, B_), blk, 0, stream>>>(
            G, EObf, mask, ae, S_, E_,
            (long long)T_ * E_, (long long)S_ * E_, (long long)T_ * S_, S_);

        // EVt[b][d][s] = EV[b][s][d]
        transpose_cast<<<dim3(D_ / 64, S_ / 64, B_), blk, 0, stream>>>(
            ev, EVT, S_, D_, (long long)S_ * D_, (long long)D_ * S_);

        // K3: softmax -> aw (fp32) + AWbf (bf16, aliases G)
        softmax_mask<<<dim3(B_ * T_), blk, 0, stream>>>(ae, mask, aw, AWbf);

        // K4: ctx = AWbf @ EVT^T   (16x4x16 = 1024 blocks)
        mfma_gemm_bf<false, false><<<dim3(D_ / 64, T_ / 128, B_), blk, 0, stream>>>(
            AWbf, EVT, nullptr, ctx, D_, S_,
            (long long)T_ * S_, (long long)D_ * S_, (long long)T_ * D_, 0);
    } else {
        float* G = aw;
        gemm_f32<false, false><<<dim3(E_ / FBN, (B_ * T_) / FBM, 1), blk, 0, stream>>>(
            hidden, W, nullptr, G, E_, D_, 0, 0, 0, 0);
        gemm_f32<true, true><<<dim3(S_ / FBN, T_ / FBM, B_), blk, 0, stream>>>(
            G, eo, mask, ae, S_, E_,
            (long long)T_ * E_, (long long)S_ * E_, (long long)T_ * S_, S_);
        softmax_mask<<<dim3(B_ * T_), blk, 0, stream>>>(ae, mask, aw, nullptr);
        gemm_f32<false, false><<<dim3(D_ / FBN, T_ / FBM, B_), blk, 0, stream>>>(
            aw, ev, nullptr, ctx, D_, S_,
            (long long)T_ * S_, (long long)S_ * D_, (long long)T_ * D_, 0);
    }
}

// Round 5
// 322.354 us; speedup vs baseline: 1.0493x; 1.0344x over previous
//
#include <hip/hip_runtime.h>
#include <math.h>

#define B_  16
#define T_  512
#define S_  1024
#define E_  1024
#define D_  1024

using short8   = __attribute__((ext_vector_type(8))) short;
using ushort4v = __attribute__((ext_vector_type(4))) unsigned short;
using float4v  = __attribute__((ext_vector_type(4))) float;

__device__ __forceinline__ unsigned short f2bf(float f) {
    unsigned u = __builtin_bit_cast(unsigned, f);
    u += 0x7fff + ((u >> 16) & 1);          // round-to-nearest-even
    return (unsigned short)(u >> 16);
}

__device__ __forceinline__ void gl_lds16(const void* g, void* l) {
    __builtin_amdgcn_global_load_lds(
        (const __attribute__((address_space(1))) void*)g,
        (__attribute__((address_space(3))) void*)l, 16, 0, 0);
}

// ---------------------------------------------------------------------------
// Fused prep (ONE launch replaces 4): casts hidden->Hbf, eo->EObf and
// transposes W->WT, EV->EVT.  Flat grid, per-block role dispatch:
//   [0,4096)        cast hidden   (8M elems, 2048/block)
//   [4096,12288)    cast eo       (16M elems)
//   [12288,12544)   transpose W   (256 64x64 tiles)
//   [12544,16640)   transpose EV  (16 x 256 tiles)
// ---------------------------------------------------------------------------
__global__ __launch_bounds__(256)
void prep_all(const float* __restrict__ hidden, unsigned short* __restrict__ Hbf,
              const float* __restrict__ W,      unsigned short* __restrict__ WT,
              const float* __restrict__ eo,     unsigned short* __restrict__ EObf,
              const float* __restrict__ ev,     unsigned short* __restrict__ EVT)
{
    __shared__ unsigned short tile[64][65];
    const int t = threadIdx.x;
    int bid = blockIdx.x;

    if (bid < 4096) {                       // cast hidden
        const int i = bid * 256 + t;
        float4 a = ((const float4*)hidden)[2 * i];
        float4 b = ((const float4*)hidden)[2 * i + 1];
        short8 o;
        o[0] = f2bf(a.x); o[1] = f2bf(a.y); o[2] = f2bf(a.z); o[3] = f2bf(a.w);
        o[4] = f2bf(b.x); o[5] = f2bf(b.y); o[6] = f2bf(b.z); o[7] = f2bf(b.w);
        ((short8*)Hbf)[i] = o;
        return;
    }
    bid -= 4096;
    if (bid < 8192) {                       // cast encoder_outputs
        const int i = bid * 256 + t;
        float4 a = ((const float4*)eo)[2 * i];
        float4 b = ((const float4*)eo)[2 * i + 1];
        short8 o;
        o[0] = f2bf(a.x); o[1] = f2bf(a.y); o[2] = f2bf(a.z); o[3] = f2bf(a.w);
        o[4] = f2bf(b.x); o[5] = f2bf(b.y); o[6] = f2bf(b.z); o[7] = f2bf(b.w);
        ((short8*)EObf)[i] = o;
        return;
    }
    bid -= 8192;
    const float* src;
    unsigned short* dst;
    if (bid < 256) {                        // transpose W (D,E)->(E,D)
        src = W; dst = WT;
    } else {                                // transpose EV[z] (S,D)->(D,S)
        bid -= 256;
        const int z = bid >> 8;
        bid &= 255;
        src = ev + (long long)z * S_ * D_;
        dst = EVT + (long long)z * D_ * S_;
    }
    const int c0 = (bid & 15) << 6;
    const int r0 = (bid >> 4) << 6;
    #pragma unroll
    for (int it = 0; it < 4; ++it) {
        int r  = (t >> 4) + it * 16;
        int c4 = (t & 15) << 2;
        float4 v = *(const float4*)&src[(long long)(r0 + r) * 1024 + c0 + c4];
        tile[r][c4 + 0] = f2bf(v.x);
        tile[r][c4 + 1] = f2bf(v.y);
        tile[r][c4 + 2] = f2bf(v.z);
        tile[r][c4 + 3] = f2bf(v.w);
    }
    __syncthreads();
    #pragma unroll
    for (int it = 0; it < 2; ++it) {
        int c  = (t >> 3) + it * 32;
        int r8 = (t & 7) << 3;
        short8 sv;
        #pragma unroll
        for (int j = 0; j < 8; ++j) sv[j] = (short)tile[r8 + j][c];
        *(short8*)&dst[(long long)(c0 + c) * 1024 + r0 + r8] = sv;
    }
}

// ---------------------------------------------------------------------------
// Standalone cast / transpose kernels — used by the mid path (64<=ws<100MB),
// identical to the R0-validated versions.
// ---------------------------------------------------------------------------
__global__ __launch_bounds__(256)
void cast_bf16(const float* __restrict__ src, unsigned short* __restrict__ dst, int n8)
{
    int i = blockIdx.x * 256 + threadIdx.x;
    if (i < n8) {
        float4 a = ((const float4*)src)[2 * i];
        float4 b = ((const float4*)src)[2 * i + 1];
        short8 o;
        o[0] = f2bf(a.x); o[1] = f2bf(a.y); o[2] = f2bf(a.z); o[3] = f2bf(a.w);
        o[4] = f2bf(b.x); o[5] = f2bf(b.y); o[6] = f2bf(b.z); o[7] = f2bf(b.w);
        ((short8*)dst)[i] = o;
    }
}

__global__ __launch_bounds__(256)
void transpose_cast(const float* __restrict__ src, unsigned short* __restrict__ dst,
                    int R, int C, long long sSrc, long long sDst)
{
    __shared__ unsigned short tile[64][65];
    const int z = blockIdx.z;
    src += (long long)z * sSrc;
    dst += (long long)z * sDst;
    const int c0 = blockIdx.x * 64;
    const int r0 = blockIdx.y * 64;
    const int t = threadIdx.x;

    #pragma unroll
    for (int it = 0; it < 4; ++it) {
        int r  = (t >> 4) + it * 16;
        int c4 = (t & 15) << 2;
        float4 v = *(const float4*)&src[(long long)(r0 + r) * C + c0 + c4];
        tile[r][c4 + 0] = f2bf(v.x);
        tile[r][c4 + 1] = f2bf(v.y);
        tile[r][c4 + 2] = f2bf(v.z);
        tile[r][c4 + 3] = f2bf(v.w);
    }
    __syncthreads();
    #pragma unroll
    for (int it = 0; it < 2; ++it) {
        int c  = (t >> 3) + it * 32;
        int r8 = (t & 7) << 3;
        short8 sv;
        #pragma unroll
        for (int j = 0; j < 8; ++j) sv[j] = (short)tile[r8 + j][c];
        *(short8*)&dst[(long long)(c0 + c) * R + r0 + r8] = sv;
    }
}

// ---------------------------------------------------------------------------
// Fast MFMA GEMM (R0-validated, best measured): C[M,N] = A @ B^T,
// A (M,K) bf16, B (N,K) bf16, row-major.  128x128 tile, BK=64 as TWO
// stacked [128][32] subtiles (m97 lane mapping), global_load_lds width-16
// staging, ds_read_b128 frags, 16x16x32 MFMA, one barrier pair per 64-k.
// ---------------------------------------------------------------------------
template<bool OUT_BF16, bool CMASK>
__global__ __launch_bounds__(256, 2)
void mfma_gemm_bf(const unsigned short* __restrict__ Ap,
                  const unsigned short* __restrict__ Bp,
                  const float* __restrict__ mask, void* __restrict__ Cp,
                  int N, int K,
                  long long sA, long long sB, long long sC, int maskStride)
{
    __shared__ unsigned short Asl[2 * 128 * 32];   // subtile j at j*4096 elems
    __shared__ unsigned short Bsl[2 * 128 * 32];

    const int z    = blockIdx.z;
    const int col0 = blockIdx.x * 128;
    const int row0 = blockIdx.y * 128;
    const int t    = threadIdx.x;
    const int lane = t & 63;
    const int wave = t >> 6;

    const unsigned short* A  = Ap + z * sA + (long long)row0 * K;
    const unsigned short* Bm = Bp + z * sB + (long long)col0 * K;

    const int rs  = t >> 2;
    const int kcs = (t & 3) << 3;
    const unsigned ldsW = wave * 1024;

    const int wm = (wave >> 1) * 64;
    const int wn = (wave & 1) * 64;
    const int fr = lane & 15;
    const int fg = lane >> 4;

    float4v acc[4][4];
    #pragma unroll
    for (int i = 0; i < 4; ++i)
        #pragma unroll
        for (int j = 0; j < 4; ++j)
            acc[i][j] = (float4v)0.0f;

    for (int k0 = 0; k0 < K; k0 += 64) {
        #pragma unroll
        for (int j = 0; j < 2; ++j) {
            #pragma unroll
            for (int it = 0; it < 2; ++it) {
                const int r = rs + it * 64;
                const long long goff = (long long)r * K + k0 + j * 32 + kcs;
                const unsigned loff = j * 8192 + it * 4096 + ldsW;
                gl_lds16(A  + goff, (char*)Asl + loff);
                gl_lds16(Bm + goff, (char*)Bsl + loff);
            }
        }
        __syncthreads();

        short8 af[2][4], bf[2][4];
        #pragma unroll
        for (int j = 0; j < 2; ++j) {
            #pragma unroll
            for (int mi = 0; mi < 4; ++mi)
                af[j][mi] = *(const short8*)&Asl[j * 4096 + (wm + mi * 16 + fr) * 32 + fg * 8];
            #pragma unroll
            for (int ni = 0; ni < 4; ++ni)
                bf[j][ni] = *(const short8*)&Bsl[j * 4096 + (wn + ni * 16 + fr) * 32 + fg * 8];
        }
        #pragma unroll
        for (int j = 0; j < 2; ++j)
            #pragma unroll
            for (int mi = 0; mi < 4; ++mi)
                #pragma unroll
                for (int ni = 0; ni < 4; ++ni)
                    acc[mi][ni] = __builtin_amdgcn_mfma_f32_16x16x32_bf16(af[j][mi], bf[j][ni], acc[mi][ni], 0, 0, 0);
        __syncthreads();
    }

    float mv[4];
    #pragma unroll
    for (int ni = 0; ni < 4; ++ni) {
        int ocol = col0 + wn + ni * 16 + fr;
        mv[ni] = CMASK ? mask[(long long)z * maskStride + ocol] : 1.0f;
    }
    #pragma unroll
    for (int mi = 0; mi < 4; ++mi) {
        #pragma unroll
        for (int ni = 0; ni < 4; ++ni) {
            int ocol = col0 + wn + ni * 16 + fr;
            #pragma unroll
            for (int r = 0; r < 4; ++r) {
                int orow = row0 + wm + mi * 16 + fg * 4 + r;
                float v = acc[mi][ni][r] * mv[ni];
                if (OUT_BF16)
                    ((unsigned short*)Cp)[z * sC + (long long)orow * N + ocol] = f2bf(v);
                else
                    ((float*)Cp)[z * sC + (long long)orow * N + ocol] = v;
            }
        }
    }
}

// ---------------------------------------------------------------------------
// Masked softmax; also writes a bf16 copy of the weights when wbf != nullptr.
// ---------------------------------------------------------------------------
__global__ __launch_bounds__(256)
void softmax_mask(const float* __restrict__ x, const float* __restrict__ mask,
                  float* __restrict__ w, unsigned short* __restrict__ wbf)
{
    const int row = blockIdx.x;
    const int b   = row >> 9;             // T_=512
    const float* xr = x    + (long long)row * S_;
    const float* mr = mask + (long long)b * S_;
    float*       wr = w    + (long long)row * S_;
    const int tid = threadIdx.x;

    float4 xv = ((const float4*)xr)[tid];
    float4 mv = ((const float4*)mr)[tid];

    float lmax = fmaxf(fmaxf(xv.x, xv.y), fmaxf(xv.z, xv.w));
    #pragma unroll
    for (int off = 32; off; off >>= 1)
        lmax = fmaxf(lmax, __shfl_xor(lmax, off, 64));

    __shared__ float red[4];
    const int wave = tid >> 6, lane = tid & 63;
    if (lane == 0) red[wave] = lmax;
    __syncthreads();
    const float rmax = fmaxf(fmaxf(red[0], red[1]), fmaxf(red[2], red[3]));

    float e0 = expf(xv.x - rmax) * mv.x;
    float e1 = expf(xv.y - rmax) * mv.y;
    float e2 = expf(xv.z - rmax) * mv.z;
    float e3 = expf(xv.w - rmax) * mv.w;

    float lsum = (e0 + e1) + (e2 + e3);
    #pragma unroll
    for (int off = 32; off; off >>= 1)
        lsum += __shfl_xor(lsum, off, 64);

    __syncthreads();
    if (lane == 0) red[wave] = lsum;
    __syncthreads();
    const float rsum = (red[0] + red[1]) + (red[2] + red[3]);
    const float inv = 1.0f / (rsum + 1e-6f);

    float4 o;
    o.x = e0 * inv; o.y = e1 * inv; o.z = e2 * inv; o.w = e3 * inv;
    ((float4*)wr)[tid] = o;
    if (wbf) {
        ushort4v u;
        u[0] = f2bf(o.x); u[1] = f2bf(o.y); u[2] = f2bf(o.z); u[3] = f2bf(o.w);
        ((ushort4v*)(wbf + (long long)row * S_))[tid] = u;
    }
}

// ---------------------------------------------------------------------------
// fp32 fallback GEMM — used only if d_ws is tiny.
// ---------------------------------------------------------------------------
constexpr int FBM = 64, FBN = 64, FBK = 16;
template<bool BT, bool CMASK>
__global__ __launch_bounds__(256)
void gemm_f32(const float* __restrict__ A, const float* __restrict__ Bm,
              const float* __restrict__ mask, float* __restrict__ C,
              int N_dim, int K_dim,
              long long sA, long long sB, long long sC, int maskStride)
{
    const int bz = blockIdx.z;
    A  += (long long)bz * sA;
    Bm += (long long)bz * sB;
    C  += (long long)bz * sC;
    __shared__ float As[FBK][FBM];
    __shared__ float Bs[FBK][FBN];
    const int tid  = threadIdx.x;
    const int row0 = blockIdx.y * FBM;
    const int col0 = blockIdx.x * FBN;
    const int lrow = tid >> 2;
    const int lk   = (tid & 3) << 2;
    const int bk = tid >> 4;
    const int bn = (tid & 15) << 2;
    const int tx = tid & 15;
    const int ty = tid >> 4;
    float acc[4][4] = {};
    const float* Aptr = A + (long long)(row0 + lrow) * K_dim + lk;
    const float* Bptr = BT ? (Bm + (long long)(col0 + lrow) * K_dim + lk)
                           : (Bm + (long long)bk * N_dim + col0 + bn);
    for (int k0 = 0; k0 < K_dim; k0 += FBK) {
        float4 av = *(const float4*)(Aptr + k0);
        As[lk + 0][lrow] = av.x; As[lk + 1][lrow] = av.y;
        As[lk + 2][lrow] = av.z; As[lk + 3][lrow] = av.w;
        if (BT) {
            float4 bv = *(const float4*)(Bptr + k0);
            Bs[lk + 0][lrow] = bv.x; Bs[lk + 1][lrow] = bv.y;
            Bs[lk + 2][lrow] = bv.z; Bs[lk + 3][lrow] = bv.w;
        } else {
            float4 bv = *(const float4*)(Bptr + (long long)k0 * N_dim);
            *(float4*)&Bs[bk][bn] = bv;
        }
        __syncthreads();
        #pragma unroll
        for (int k = 0; k < FBK; ++k) {
            float4 a4 = *(const float4*)&As[k][ty << 2];
            float4 b4 = *(const float4*)&Bs[k][tx << 2];
            float ar[4] = {a4.x, a4.y, a4.z, a4.w};
            float br[4] = {b4.x, b4.y, b4.z, b4.w};
            #pragma unroll
            for (int i = 0; i < 4; ++i)
                #pragma unroll
                for (int j = 0; j < 4; ++j)
                    acc[i][j] = fmaf(ar[i], br[j], acc[i][j]);
        }
        __syncthreads();
    }
    float mvv[4] = {1.f, 1.f, 1.f, 1.f};
    if (CMASK) {
        #pragma unroll
        for (int j = 0; j < 4; ++j)
            mvv[j] = mask[(long long)bz * maskStride + col0 + (tx << 2) + j];
    }
    #pragma unroll
    for (int i = 0; i < 4; ++i) {
        const int r = row0 + (ty << 2) + i;
        float4 o;
        o.x = acc[i][0] * mvv[0]; o.y = acc[i][1] * mvv[1];
        o.z = acc[i][2] * mvv[2]; o.w = acc[i][3] * mvv[3];
        *(float4*)&C[(long long)r * N_dim + col0 + (tx << 2)] = o;
    }
}

extern "C" void kernel_launch(void* const* d_in, const int* in_sizes, int n_in,
                              void* d_out, int out_size, void* d_ws, size_t ws_size,
                              hipStream_t stream)
{
    const float* hidden = (const float*)d_in[0];   // (B,T,D)
    const float* eo     = (const float*)d_in[1];   // (B,S,E)
    const float* ev     = (const float*)d_in[2];   // (B,S,D)
    const float* mask   = (const float*)d_in[3];   // (B,S)
    const float* W      = (const float*)d_in[4];   // (D,E)

    float* out = (float*)d_out;
    const long long CTX = (long long)B_ * T_ * D_;
    float* ctx = out;
    float* aw  = out + CTX;
    float* ae  = out + 2 * CTX;

    dim3 blk(256);
    const size_t MB = 1024ull * 1024ull;

    if (ws_size >= 100 * MB) {
        // De-aliased layout (all prep products coexist):
        //   Hbf [0,16) | WT [16,18) | G [18,34) | EObf [34,66) | EVT [66,98)
        //   AWbf aliases Hbf [0,16) (Hbf dead after K1; AWbf written by K3)
        char* ws = (char*)d_ws;
        unsigned short* Hbf  = (unsigned short*)(ws);
        unsigned short* WT   = (unsigned short*)(ws + 16 * MB);
        unsigned short* G    = (unsigned short*)(ws + 18 * MB);
        unsigned short* EObf = (unsigned short*)(ws + 34 * MB);
        unsigned short* EVT  = (unsigned short*)(ws + 66 * MB);
        unsigned short* AWbf = (unsigned short*)(ws);

        // P0: all casts + transposes in one launch
        prep_all<<<dim3(16640), blk, 0, stream>>>(hidden, Hbf, W, WT, eo, EObf, ev, EVT);

        // K1: G = Hbf @ WT^T -> bf16
        mfma_gemm_bf<true, false><<<dim3(E_ / 128, (B_ * T_) / 128, 1), blk, 0, stream>>>(
            Hbf, WT, nullptr, G, E_, D_, 0, 0, 0, 0);

        // K2: ae[b,t,s] = mask[b,s] * (G[b,t,:] . EObf[b,s,:])
        mfma_gemm_bf<false, true><<<dim3(S_ / 128, T_ / 128, B_), blk, 0, stream>>>(
            G, EObf, mask, ae, S_, E_,
            (long long)T_ * E_, (long long)S_ * E_, (long long)T_ * S_, S_);

        // K3: softmax -> aw (fp32) + AWbf (bf16)
        softmax_mask<<<dim3(B_ * T_), blk, 0, stream>>>(ae, mask, aw, AWbf);

        // K4: ctx = AWbf @ EVT^T
        mfma_gemm_bf<false, false><<<dim3(D_ / 128, T_ / 128, B_), blk, 0, stream>>>(
            AWbf, EVT, nullptr, ctx, D_, S_,
            (long long)T_ * S_, (long long)D_ * S_, (long long)T_ * D_, 0);
    } else if (ws_size >= 64 * MB) {
        // R0-validated 8-kernel flow with live-range aliasing:
        //   [0,16) Hbf -> EObf [0,32) after K1 | [16,18) WT | [16,48) EVT
        //   [48,64) G -> AWbf
        char* ws = (char*)d_ws;
        unsigned short* Hbf  = (unsigned short*)(ws);
        unsigned short* WT   = (unsigned short*)(ws + 16 * MB);
        unsigned short* EObf = (unsigned short*)(ws);
        unsigned short* EVT  = (unsigned short*)(ws + 16 * MB);
        unsigned short* G    = (unsigned short*)(ws + 48 * MB);
        unsigned short* AWbf = (unsigned short*)(ws + 48 * MB);

        cast_bf16<<<dim3((B_ * T_ * D_ / 8 + 255) / 256), blk, 0, stream>>>(
            hidden, Hbf, B_ * T_ * D_ / 8);
        transpose_cast<<<dim3(E_ / 64, D_ / 64, 1), blk, 0, stream>>>(
            W, WT, D_, E_, 0, 0);
        mfma_gemm_bf<true, false><<<dim3(E_ / 128, (B_ * T_) / 128, 1), blk, 0, stream>>>(
            Hbf, WT, nullptr, G, E_, D_, 0, 0, 0, 0);
        cast_bf16<<<dim3((B_ * S_ * E_ / 8 + 255) / 256), blk, 0, stream>>>(
            eo, EObf, B_ * S_ * E_ / 8);
        mfma_gemm_bf<false, true><<<dim3(S_ / 128, T_ / 128, B_), blk, 0, stream>>>(
            G, EObf, mask, ae, S_, E_,
            (long long)T_ * E_, (long long)S_ * E_, (long long)T_ * S_, S_);
        transpose_cast<<<dim3(D_ / 64, S_ / 64, B_), blk, 0, stream>>>(
            ev, EVT, S_, D_, (long long)S_ * D_, (long long)D_ * S_);
        softmax_mask<<<dim3(B_ * T_), blk, 0, stream>>>(ae, mask, aw, AWbf);
        mfma_gemm_bf<false, false><<<dim3(D_ / 128, T_ / 128, B_), blk, 0, stream>>>(
            AWbf, EVT, nullptr, ctx, D_, S_,
            (long long)T_ * S_, (long long)D_ * S_, (long long)T_ * D_, 0);
    } else {
        float* G = aw;
        gemm_f32<false, false><<<dim3(E_ / FBN, (B_ * T_) / FBM, 1), blk, 0, stream>>>(
            hidden, W, nullptr, G, E_, D_, 0, 0, 0, 0);
        gemm_f32<true, true><<<dim3(S_ / FBN, T_ / FBM, B_), blk, 0, stream>>>(
            G, eo, mask, ae, S_, E_,
            (long long)T_ * E_, (long long)S_ * E_, (long long)T_ * S_, S_);
        softmax_mask<<<dim3(B_ * T_), blk, 0, stream>>>(ae, mask, aw, nullptr);
        gemm_f32<false, false><<<dim3(D_ / FBN, T_ / FBM, B_), blk, 0, stream>>>(
            aw, ev, nullptr, ctx, D_, S_,
            (long long)T_ * S_, (long long)S_ * D_, (long long)T_ * D_, 0);
    }
}